// Round 3
// baseline (1548.612 us; speedup 1.0000x reference)
//
#include <hip/hip_runtime.h>
#include <hip/hip_bf16.h>
#include <stdint.h>

typedef __hip_bfloat16 bf16;

#define DEVFN __device__ __forceinline__

// Problem constants: B=8, N=1024, DIM=768, HEADS=8, HEAD_DIM=96, S=16, CH=3
// ALL harness tensors are float32 (per reference setup_inputs).
constexpr float SCALE = 0.10206207261596577f;   // 96^-0.5

DEVFN float blo(unsigned u) { return __uint_as_float(u << 16); }
DEVFN float bhi(unsigned u) { return __uint_as_float(u & 0xffff0000u); }

// ---------------------------------------------------------------------------
// Kernel A: 3x3 SAME conv on the (16,16,3) image view of each (b,n) row of
// q,k,v, then split into heads: head = y>>1, d = (y&1)*48 + x*3 + c.
// Inputs fp32; outputs qh/kh/vh as bf16 [B][H][N][96].
// ---------------------------------------------------------------------------
__global__ __launch_bounds__(256) void conv_kernel(
    const float* __restrict__ q, const float* __restrict__ k, const float* __restrict__ v,
    const float* __restrict__ cw,
    bf16* __restrict__ qh, bf16* __restrict__ kh, bf16* __restrict__ vh)
{
  __shared__ float img[3][768];
  __shared__ float wsm[81];
  const int t = threadIdx.x;
  const size_t pos = blockIdx.x;            // b*1024 + n
  const int b = blockIdx.x >> 10;
  const int n = blockIdx.x & 1023;

  {
    const float* s0 = q + pos * 768;
    const float* s1 = k + pos * 768;
    const float* s2 = v + pos * 768;
    img[0][t]       = s0[t];
    img[0][t + 256] = s0[t + 256];
    img[0][t + 512] = s0[t + 512];
    img[1][t]       = s1[t];
    img[1][t + 256] = s1[t + 256];
    img[1][t + 512] = s1[t + 512];
    img[2][t]       = s2[t];
    img[2][t + 256] = s2[t + 256];
    img[2][t + 512] = s2[t + 512];
  }
  if (t < 81) wsm[t] = cw[t];
  __syncthreads();

  #pragma unroll
  for (int s3 = 0; s3 < 3; ++s3) {
    bf16* dst = (s3 == 0) ? qh : (s3 == 1) ? kh : vh;
    #pragma unroll
    for (int r = 0; r < 3; ++r) {
      const int f  = t + r * 256;           // output flat index (y,x,co)
      const int co = f % 3;
      const int x  = (f / 3) & 15;
      const int y  = f / 48;
      float acc = 0.f;
      #pragma unroll
      for (int dy = 0; dy < 3; ++dy) {
        const int iy = y + dy - 1;
        if ((unsigned)iy < 16u) {
          #pragma unroll
          for (int dx = 0; dx < 3; ++dx) {
            const int ix = x + dx - 1;
            if ((unsigned)ix < 16u) {
              const int ib = iy * 48 + ix * 3;
              const int wb = (dy * 3 + dx) * 9 + co;  // w[dy][dx][ci][co], ci stride 3
              acc = fmaf(img[s3][ib + 0], wsm[wb + 0], acc);
              acc = fmaf(img[s3][ib + 1], wsm[wb + 3], acc);
              acc = fmaf(img[s3][ib + 2], wsm[wb + 6], acc);
            }
          }
        }
      }
      const int head = y >> 1;
      const int d    = (y & 1) * 48 + x * 3 + co;
      dst[(((size_t)(b * 8 + head)) * 1024 + n) * 96 + d] = __float2bfloat16(acc);
    }
  }
}

// ---------------------------------------------------------------------------
// Kernel B: vsum[b][g][d] = sum_m vh[b][g][m][d]  (fp32)
// ---------------------------------------------------------------------------
__global__ __launch_bounds__(128) void vsum_kernel(
    const bf16* __restrict__ vh, float* __restrict__ vsum)
{
  const int bg = blockIdx.x;                // b*8 + g  (64 blocks)
  const int d = threadIdx.x;
  if (d >= 96) return;
  const bf16* base = vh + (size_t)bg * 1024 * 96;
  float acc = 0.f;
  for (int m = 0; m < 1024; ++m) acc += __bfloat162float(base[(size_t)m * 96 + d]);
  vsum[bg * 96 + d] = acc;
}

// ---------------------------------------------------------------------------
// Kernel C: fused two-pass attention with head re-mixing.
// LDS tiles are `unsigned` (bf16 pairs) staged with uint4 loads.
// ---------------------------------------------------------------------------
DEVFN void mac22(unsigned a0, unsigned a1, unsigned b0, unsigned b1,
                 float& s00, float& s01, float& s10, float& s11)
{
  const float a0l = blo(a0), a0h = bhi(a0), a1l = blo(a1), a1h = bhi(a1);
  const float b0l = blo(b0), b0h = bhi(b0), b1l = blo(b1), b1h = bhi(b1);
  s00 = fmaf(a0l, b0l, s00); s00 = fmaf(a0h, b0h, s00);
  s01 = fmaf(a0l, b1l, s01); s01 = fmaf(a0h, b1h, s01);
  s10 = fmaf(a1l, b0l, s10); s10 = fmaf(a1h, b0h, s10);
  s11 = fmaf(a1l, b1l, s11); s11 = fmaf(a1h, b1h, s11);
}

DEVFN void dot2x2(const unsigned* __restrict__ qa, const unsigned* __restrict__ qb,
                  const unsigned* __restrict__ ka, const unsigned* __restrict__ kb,
                  float& s00, float& s01, float& s10, float& s11)
{
  float t00 = 0.f, t01 = 0.f, t10 = 0.f, t11 = 0.f;
  #pragma unroll
  for (int jj = 0; jj < 12; ++jj) {         // 12 * 4 pairs = 96 bf16 elements
    const uint4 A0 = ((const uint4*)qa)[jj];
    const uint4 A1 = ((const uint4*)qb)[jj];
    const uint4 B0 = ((const uint4*)ka)[jj];
    const uint4 B1 = ((const uint4*)kb)[jj];
    mac22(A0.x, A1.x, B0.x, B1.x, t00, t01, t10, t11);
    mac22(A0.y, A1.y, B0.y, B1.y, t00, t01, t10, t11);
    mac22(A0.z, A1.z, B0.z, B1.z, t00, t01, t10, t11);
    mac22(A0.w, A1.w, B0.w, B1.w, t00, t01, t10, t11);
  }
  s00 = t00 * SCALE; s01 = t01 * SCALE; s10 = t10 * SCALE; s11 = t11 * SCALE;
}

// Stage 64 rows x 96 bf16 (= 12 uint4 per row) from global into LDS.
// src rows are 192 B apart and 16 B aligned.
DEVFN void stage64(const bf16* __restrict__ src, unsigned (*__restrict__ dst)[52], int t)
{
  #pragma unroll
  for (int it = 0; it < 3; ++it) {          // 64*12 = 768 uint4 = 3*256
    const int i = t + it * 256;
    const int r = i / 12;
    const int j = i - r * 12;
    ((uint4*)&dst[r][0])[j] = ((const uint4*)(src + (size_t)r * 96))[j];
  }
}

__global__ __launch_bounds__(256) void attn_kernel(
    const bf16* __restrict__ qh, const bf16* __restrict__ kh, const bf16* __restrict__ vh,
    const float* __restrict__ vsum,
    const float* __restrict__ rw, const float* __restrict__ rb,
    const float* __restrict__ bng, const float* __restrict__ bnb,
    const float* __restrict__ bnm, const float* __restrict__ bnv,
    float* __restrict__ X)
{
  __shared__ __align__(16) unsigned Qs[8][16][52];  // 48 used + 4 pad (208B stride)
  __shared__ __align__(16) unsigned Ks[64][52];     // K tile (per h) or V tile (per g)
  __shared__ bf16 Am[8][16][66];                    // mixed attention tile, bf16
  __shared__ float Ml[8][16], Ll[8][16];            // per-head row max & 1/sum
  __shared__ float Wm[8][8];
  __shared__ float invg[8], cg[8];

  const int t  = threadIdx.x;
  const int b  = blockIdx.x >> 6;
  const int n0 = (blockIdx.x & 63) << 4;

  // stage all-head Q tile: 8*16 rows x 12 uint4 = 1536 uint4 = 6*256
  #pragma unroll
  for (int it = 0; it < 6; ++it) {
    const int i = t + it * 256;
    const int h = i / 192;
    const int rem = i - h * 192;
    const int r = rem / 12;
    const int j = rem - r * 12;
    const uint4* src = (const uint4*)(qh + (((size_t)(b * 8 + h)) * 1024 + (n0 + r)) * 96);
    ((uint4*)&Qs[h][r][0])[j] = src[j];
  }
  if (t < 64) Wm[t >> 3][t & 7] = rw[t];
  if (t < 8) {
    const float iv = bng[t] * rsqrtf(bnv[t] + 1e-3f);
    invg[t] = iv;
    cg[t] = iv * (rb[t] - bnm[t]) + bnb[t];
  }

  const int np = t >> 5, mg = t & 31;
  const int r0 = np, r1 = np + 8;

  // ------------------- pass 1: softmax stats (M, 1/L) per (h, row) --------
  for (int h = 0; h < 8; ++h) {
    float mr0 = -1e30f, mr1 = -1e30f, lr0 = 0.f, lr1 = 0.f;
    const bf16* kbase = kh + ((size_t)(b * 8 + h)) * 1024 * 96;
    for (int m0 = 0; m0 < 1024; m0 += 64) {
      __syncthreads();
      stage64(kbase + (size_t)m0 * 96, Ks, t);
      __syncthreads();
      float s00, s01, s10, s11;
      dot2x2(&Qs[h][r0][0], &Qs[h][r1][0], &Ks[mg][0], &Ks[mg + 32][0],
             s00, s01, s10, s11);
      {
        const float nm = fmaxf(mr0, fmaxf(s00, s01));
        lr0 = lr0 * __expf(mr0 - nm) + __expf(s00 - nm) + __expf(s01 - nm);
        mr0 = nm;
      }
      {
        const float nm = fmaxf(mr1, fmaxf(s10, s11));
        lr1 = lr1 * __expf(mr1 - nm) + __expf(s10 - nm) + __expf(s11 - nm);
        mr1 = nm;
      }
    }
    #pragma unroll
    for (int off = 1; off <= 16; off <<= 1) {     // reduce across the 32 mg lanes
      float om = __shfl_xor(mr0, off); float ol = __shfl_xor(lr0, off);
      float nm = fmaxf(mr0, om);
      lr0 = lr0 * __expf(mr0 - nm) + ol * __expf(om - nm); mr0 = nm;
      om = __shfl_xor(mr1, off); ol = __shfl_xor(lr1, off);
      nm = fmaxf(mr1, om);
      lr1 = lr1 * __expf(mr1 - nm) + ol * __expf(om - nm); mr1 = nm;
    }
    if (mg == 0) {
      Ml[h][r0] = mr0; Ll[h][r0] = 1.f / lr0;
      Ml[h][r1] = mr1; Ll[h][r1] = 1.f / lr1;
    }
  }
  __syncthreads();

  // ------------------- pass 2: P, head-mix, PV ----------------------------
  const int n2 = t >> 4, dsl = t & 15;
  float acc[8][6];
  #pragma unroll
  for (int g = 0; g < 8; ++g)
    #pragma unroll
    for (int dd = 0; dd < 6; ++dd) acc[g][dd] = 0.f;

  for (int m0 = 0; m0 < 1024; m0 += 64) {
    float aloc[8][4];
    #pragma unroll
    for (int g = 0; g < 8; ++g) { aloc[g][0] = aloc[g][1] = aloc[g][2] = aloc[g][3] = 0.f; }

    for (int h = 0; h < 8; ++h) {
      __syncthreads();
      stage64(kh + (((size_t)(b * 8 + h)) * 1024 + m0) * 96, Ks, t);
      __syncthreads();
      float s00, s01, s10, s11;
      dot2x2(&Qs[h][r0][0], &Qs[h][r1][0], &Ks[mg][0], &Ks[mg + 32][0],
             s00, s01, s10, s11);
      // clamp: scores are recomputed identically to pass 1, so s <= M holds;
      // the clamp makes inf impossible even if they differ by an ulp.
      const float p00 = __expf(fminf(s00 - Ml[h][r0], 0.f)) * Ll[h][r0];
      const float p01 = __expf(fminf(s01 - Ml[h][r0], 0.f)) * Ll[h][r0];
      const float p10 = __expf(fminf(s10 - Ml[h][r1], 0.f)) * Ll[h][r1];
      const float p11 = __expf(fminf(s11 - Ml[h][r1], 0.f)) * Ll[h][r1];
      #pragma unroll
      for (int g = 0; g < 8; ++g) {
        const float w = Wm[h][g];
        aloc[g][0] = fmaf(p00, w, aloc[g][0]);
        aloc[g][1] = fmaf(p01, w, aloc[g][1]);
        aloc[g][2] = fmaf(p10, w, aloc[g][2]);
        aloc[g][3] = fmaf(p11, w, aloc[g][3]);
      }
    }
    // publish mixed-attention tile (cols mg, mg+32; rows r0, r1)
    #pragma unroll
    for (int g = 0; g < 8; ++g) {
      Am[g][r0][mg]      = __float2bfloat16(aloc[g][0]);
      Am[g][r0][mg + 32] = __float2bfloat16(aloc[g][1]);
      Am[g][r1][mg]      = __float2bfloat16(aloc[g][2]);
      Am[g][r1][mg + 32] = __float2bfloat16(aloc[g][3]);
    }
    for (int g = 0; g < 8; ++g) {
      __syncthreads();                              // Am visible / Ks reads done
      stage64(vh + (((size_t)(b * 8 + g)) * 1024 + m0) * 96, Ks, t);
      __syncthreads();
      const bf16* arow = &Am[g][n2][0];
      for (int mi = 0; mi < 64; ++mi) {
        const float a = __bfloat162float(arow[mi]);
        const unsigned u0 = Ks[mi][dsl * 3 + 0];
        const unsigned u1 = Ks[mi][dsl * 3 + 1];
        const unsigned u2 = Ks[mi][dsl * 3 + 2];
        acc[g][0] = fmaf(a, blo(u0), acc[g][0]);
        acc[g][1] = fmaf(a, bhi(u0), acc[g][1]);
        acc[g][2] = fmaf(a, blo(u1), acc[g][2]);
        acc[g][3] = fmaf(a, bhi(u1), acc[g][3]);
        acc[g][4] = fmaf(a, blo(u2), acc[g][4]);
        acc[g][5] = fmaf(a, bhi(u2), acc[g][5]);
      }
    }
  }

  // epilogue: X[b, n, g*96+d] = inv[g]*acc + c[g]*vsum[b,g,d]
  #pragma unroll
  for (int g = 0; g < 8; ++g) {
    const float iv = invg[g], cc = cg[g];
    #pragma unroll
    for (int dd = 0; dd < 6; ++dd) {
      const int d = dsl * 6 + dd;
      const float r = fmaf(iv, acc[g][dd], cc * vsum[(b * 8 + g) * 96 + d]);
      X[((size_t)(b * 1024 + n0 + n2)) * 768 + g * 96 + d] = r;
    }
  }
}

// ---------------------------------------------------------------------------
// Kernel D: out = X @ proj_w + proj_b    (8192x768) @ (768x768), fp32
// 64x64 tiles, k-tile 16, 4x4 per thread.
// ---------------------------------------------------------------------------
__global__ __launch_bounds__(256) void proj_kernel(
    const float* __restrict__ X, const float* __restrict__ pw, const float* __restrict__ pb,
    float* __restrict__ out)
{
  __shared__ float Xs[64][17];
  __shared__ float Ws[16][65];
  const int t = threadIdx.x;
  const int bc = blockIdx.x % 12, br = blockIdx.x / 12;
  const int row0 = br * 64, col0 = bc * 64;
  const int tn = t >> 4, tc = t & 15;
  float acc2[4][4] = {{0.f}};

  for (int kt = 0; kt < 768; kt += 16) {
    __syncthreads();
    #pragma unroll
    for (int it = 0; it < 4; ++it) {
      const int idx = t + it * 256;
      const int r = idx >> 4, kk = idx & 15;
      Xs[r][kk] = X[(size_t)(row0 + r) * 768 + kt + kk];
    }
    #pragma unroll
    for (int it = 0; it < 4; ++it) {
      const int idx = t + it * 256;
      const int kk = idx >> 6, c = idx & 63;
      Ws[kk][c] = pw[(size_t)(kt + kk) * 768 + col0 + c];
    }
    __syncthreads();
    #pragma unroll
    for (int kk = 0; kk < 16; ++kk) {
      float a[4], bb4[4];
      #pragma unroll
      for (int i = 0; i < 4; ++i) a[i] = Xs[tn + 16 * i][kk];
      #pragma unroll
      for (int j = 0; j < 4; ++j) bb4[j] = Ws[kk][tc + 16 * j];
      #pragma unroll
      for (int i = 0; i < 4; ++i)
        #pragma unroll
        for (int j = 0; j < 4; ++j)
          acc2[i][j] = fmaf(a[i], bb4[j], acc2[i][j]);
    }
  }
  #pragma unroll
  for (int i = 0; i < 4; ++i)
    #pragma unroll
    for (int j = 0; j < 4; ++j) {
      const int c = col0 + tc + 16 * j;
      out[(size_t)(row0 + tn + 16 * i) * 768 + c] = acc2[i][j] + pb[c];
    }
}

// ---------------------------------------------------------------------------
extern "C" void kernel_launch(void* const* d_in, const int* in_sizes, int n_in,
                              void* d_out, int out_size, void* d_ws, size_t ws_size,
                              hipStream_t stream)
{
  const float* q  = (const float*)d_in[0];
  const float* k  = (const float*)d_in[1];
  const float* v  = (const float*)d_in[2];
  const float* cw = (const float*)d_in[3];
  const float* rw = (const float*)d_in[4];
  const float* rb = (const float*)d_in[5];
  const float* bg = (const float*)d_in[6];
  const float* bb = (const float*)d_in[7];
  const float* bm = (const float*)d_in[8];
  const float* bv = (const float*)d_in[9];
  const float* pw = (const float*)d_in[10];
  const float* pb = (const float*)d_in[11];
  float* out = (float*)d_out;

  char* ws = (char*)d_ws;
  // bf16 [8][8][1024][96] each = 12,582,912 B
  bf16*  qh = (bf16*)(ws);
  bf16*  kh = (bf16*)(ws + 12582912);
  bf16*  vh = (bf16*)(ws + 25165824);
  float* vs = (float*)(ws + 37748736);            // 8*8*96 fp32 = 24,576 B
  float* X  = (float*)(ws + 37773312);            // 8*1024*768 fp32 = 25,165,824 B
  // total ws usage: 62,939,136 B (~60 MB)

  conv_kernel<<<8192, 256, 0, stream>>>(q, k, v, cw, qh, kh, vh);
  vsum_kernel<<<64, 128, 0, stream>>>(vh, vs);
  attn_kernel<<<512, 256, 0, stream>>>(qh, kh, vh, vs, rw, rb, bg, bb, bm, bv, X);
  proj_kernel<<<1536, 256, 0, stream>>>(X, pw, pb, out);
}

// Round 4
// 650.415 us; speedup vs baseline: 2.3810x; 2.3810x over previous
//
#include <hip/hip_runtime.h>
#include <hip/hip_bf16.h>
#include <stdint.h>

typedef __hip_bfloat16 bf16;
typedef __attribute__((ext_vector_type(8))) short short8;  // 8 bf16 = 4 VGPR
typedef __attribute__((ext_vector_type(4))) float f32x4;

#define DEVFN __device__ __forceinline__

// B=8, N=1024, DIM=768, HEADS=8, HEAD_DIM=96, S=16, CH=3. Inputs/outputs fp32.
constexpr float SCALE = 0.10206207261596577f;   // 96^-0.5

DEVFN short8 as_s8(uint4 u) { union { uint4 a; short8 b; } x; x.a = u; return x.b; }

DEVFN f32x4 mfma16(uint4 a, uint4 b, f32x4 c) {
  return __builtin_amdgcn_mfma_f32_16x16x32_bf16(as_s8(a), as_s8(b), c, 0, 0, 0);
}

// ---------------------------------------------------------------------------
// Kernel A: 3x3 SAME conv on (16,16,3) image view; head = y>>1,
// d = (y&1)*48 + x*3 + c.  fp32 in -> bf16 qh/kh/vh [B*H][1024][96].
// ---------------------------------------------------------------------------
__global__ __launch_bounds__(256) void conv_kernel(
    const float* __restrict__ q, const float* __restrict__ k, const float* __restrict__ v,
    const float* __restrict__ cw,
    bf16* __restrict__ qh, bf16* __restrict__ kh, bf16* __restrict__ vh)
{
  __shared__ float img[3][768];
  __shared__ float wsm[81];
  const int t = threadIdx.x;
  const size_t pos = blockIdx.x;            // b*1024 + n
  const int b = blockIdx.x >> 10;
  const int n = blockIdx.x & 1023;

  {
    const float* s0 = q + pos * 768;
    const float* s1 = k + pos * 768;
    const float* s2 = v + pos * 768;
    img[0][t] = s0[t]; img[0][t + 256] = s0[t + 256]; img[0][t + 512] = s0[t + 512];
    img[1][t] = s1[t]; img[1][t + 256] = s1[t + 256]; img[1][t + 512] = s1[t + 512];
    img[2][t] = s2[t]; img[2][t + 256] = s2[t + 256]; img[2][t + 512] = s2[t + 512];
  }
  if (t < 81) wsm[t] = cw[t];
  __syncthreads();

  #pragma unroll
  for (int s3 = 0; s3 < 3; ++s3) {
    bf16* dst = (s3 == 0) ? qh : (s3 == 1) ? kh : vh;
    #pragma unroll
    for (int r = 0; r < 3; ++r) {
      const int f  = t + r * 256;           // (y,x,co)
      const int co = f % 3;
      const int x  = (f / 3) & 15;
      const int y  = f / 48;
      float acc = 0.f;
      #pragma unroll
      for (int dy = 0; dy < 3; ++dy) {
        const int iy = y + dy - 1;
        if ((unsigned)iy < 16u) {
          #pragma unroll
          for (int dx = 0; dx < 3; ++dx) {
            const int ix = x + dx - 1;
            if ((unsigned)ix < 16u) {
              const int ib = iy * 48 + ix * 3;
              const int wb = (dy * 3 + dx) * 9 + co;
              acc = fmaf(img[s3][ib + 0], wsm[wb + 0], acc);
              acc = fmaf(img[s3][ib + 1], wsm[wb + 3], acc);
              acc = fmaf(img[s3][ib + 2], wsm[wb + 6], acc);
            }
          }
        }
      }
      const int head = y >> 1;
      const int d    = (y & 1) * 48 + x * 3 + co;
      dst[(((size_t)(b * 8 + head)) * 1024 + n) * 96 + d] = __float2bfloat16(acc);
    }
  }
}

// ---------------------------------------------------------------------------
// Kernel T: transpose vh [bg][1024 n][96 d] -> vt [bg][96 d][1024 n] (bf16)
// ---------------------------------------------------------------------------
__global__ __launch_bounds__(256) void vtrans_kernel(
    const bf16* __restrict__ vh, bf16* __restrict__ vt)
{
  __shared__ unsigned T[64][52];            // 64 n-rows x 96 bf16 (48 words) + pad
  const int t = threadIdx.x;
  const int bg = blockIdx.x >> 4;           // 0..63
  const int n0 = (blockIdx.x & 15) << 6;    // 0..960
  const bf16* src = vh + ((size_t)bg * 1024 + n0) * 96;
  #pragma unroll
  for (int it = 0; it < 3; ++it) {
    const int i = t + it * 256;             // 0..767
    const int r = i / 12, j = i - r * 12;
    ((uint4*)&T[r][0])[j] = ((const uint4*)(src + (size_t)r * 96))[j];
  }
  __syncthreads();
  #pragma unroll
  for (int it = 0; it < 3; ++it) {
    const int i = t + it * 256;             // 0..767
    const int d = i >> 3, c = i & 7;        // d 0..95, 8-wide n chunk c
    unsigned wo[4];
    #pragma unroll
    for (int p = 0; p < 4; ++p) {
      const unsigned lo = T[c * 8 + p * 2    ][d >> 1];
      const unsigned hi = T[c * 8 + p * 2 + 1][d >> 1];
      const unsigned a  = (d & 1) ? (lo >> 16)          : (lo & 0xffffu);
      const unsigned bs = (d & 1) ? (hi & 0xffff0000u)  : (hi << 16);
      wo[p] = a | bs;
    }
    uint4 out4; out4.x = wo[0]; out4.y = wo[1]; out4.z = wo[2]; out4.w = wo[3];
    *(uint4*)(vt + ((size_t)bg * 96 + d) * 1024 + n0 + c * 8) = out4;
  }
}

// ---------------------------------------------------------------------------
// Kernel C: MFMA attention. Block = (b, 16 q-rows), 4 waves.
// Wave w owns m-quadrant (w*16) of each 64-wide m-tile for QK, and
// d-tiles {w} and {4+(w>>1), g-half} for PV.
// Pass 1: L[h][n] = sum_m exp(s) (no-max softmax; s bounded ~1, clamp 25).
// Pass 2: p = exp(s)/L -> a_final = inv_g * sum_h W[h,g] p_h + c_g (folds
//         reatten bias + BN; constant term reproduces the vsum path) -> PV.
// ---------------------------------------------------------------------------
__global__ __launch_bounds__(256, 2) void attn_kernel(
    const bf16* __restrict__ qh, const bf16* __restrict__ kh, const bf16* __restrict__ vt,
    const float* __restrict__ rw, const float* __restrict__ rb,
    const float* __restrict__ bng, const float* __restrict__ bnb,
    const float* __restrict__ bnm, const float* __restrict__ bnv,
    float* __restrict__ X)
{
  __shared__ bf16 Am[8][16][88];            // a_final tile; stride 88 (16B align, 2-way banks)
  __shared__ float Lp[4][8][16];
  __shared__ float Linv[8][16];
  __shared__ float Wm[8][8];
  __shared__ float invg[8], cg[8];

  const int t    = threadIdx.x;
  const int b    = blockIdx.x & 7;          // XCD swizzle: all of b's K/V on one XCD
  const int n0   = (blockIdx.x >> 3) << 4;
  const int w    = t >> 6;
  const int lane = t & 63;
  const int l15  = lane & 15;
  const int quad = lane >> 4;

  if (t < 64) Wm[t >> 3][t & 7] = rw[t];
  if (t < 8) {
    const float iv = bng[t] * rsqrtf(bnv[t] + 1e-3f);
    invg[t] = iv;
    cg[t]   = iv * (rb[t] - bnm[t]) + bnb[t];
  }

  // Preload Q A-fragments: A[row=l15][k = ks*32 + quad*8 + j]
  uint4 qf[8][3];
  #pragma unroll
  for (int h = 0; h < 8; ++h) {
    const bf16* qrow = qh + (((size_t)(b * 8 + h)) * 1024 + n0 + l15) * 96 + quad * 8;
    #pragma unroll
    for (int ks = 0; ks < 3; ++ks)
      qf[h][ks] = *(const uint4*)(qrow + ks * 32);
  }

  // ---------------- pass 1: row sums L ----------------
  #pragma unroll 1
  for (int h = 0; h < 8; ++h) {
    const bf16* kbase = kh + ((size_t)(b * 8 + h)) * 1024 * 96
                        + (size_t)(w * 16 + l15) * 96 + quad * 8;
    float lac[4] = {0.f, 0.f, 0.f, 0.f};
    uint4 c0 = *(const uint4*)(kbase);
    uint4 c1 = *(const uint4*)(kbase + 32);
    uint4 c2 = *(const uint4*)(kbase + 64);
    #pragma unroll 1
    for (int m0 = 0; m0 < 1024; m0 += 64) {
      const int mn = (m0 + 64 < 1024) ? m0 + 64 : m0;   // prefetch next tile
      const bf16* kn = kbase + (size_t)mn * 96;
      uint4 p0 = *(const uint4*)(kn);
      uint4 p1 = *(const uint4*)(kn + 32);
      uint4 p2 = *(const uint4*)(kn + 64);
      f32x4 acc = {0.f, 0.f, 0.f, 0.f};
      acc = mfma16(qf[h][0], c0, acc);
      acc = mfma16(qf[h][1], c1, acc);
      acc = mfma16(qf[h][2], c2, acc);
      #pragma unroll
      for (int r = 0; r < 4; ++r)
        lac[r] += __expf(fminf(acc[r] * SCALE, 25.f));
      c0 = p0; c1 = p1; c2 = p2;
    }
    #pragma unroll
    for (int off = 1; off < 16; off <<= 1) {
      #pragma unroll
      for (int r = 0; r < 4; ++r) lac[r] += __shfl_xor(lac[r], off);
    }
    if (l15 == 0) {
      #pragma unroll
      for (int r = 0; r < 4; ++r) Lp[w][h][quad * 4 + r] = lac[r];
    }
  }
  __syncthreads();
  if (t < 128) {
    const int h = t >> 4, n = t & 15;
    Linv[h][n] = 1.f / (Lp[0][h][n] + Lp[1][h][n] + Lp[2][h][n] + Lp[3][h][n]);
  }
  __syncthreads();

  // ---------------- pass 2: P, head-mix, PV ----------------
  const int dtA = w;                 // d-tile for phase A (all 8 g)
  const int dtB = 4 + (w >> 1);      // d-tile for phase B (4 g)
  const int gB0 = (w & 1) * 4;

  float accA[8][4], accB[4][4];
  #pragma unroll
  for (int g = 0; g < 8; ++g)
    #pragma unroll
    for (int r = 0; r < 4; ++r) accA[g][r] = 0.f;
  #pragma unroll
  for (int g = 0; g < 4; ++g)
    #pragma unroll
    for (int r = 0; r < 4; ++r) accB[g][r] = 0.f;

  const size_t koff = (size_t)(w * 16 + l15) * 96 + quad * 8;

  #pragma unroll 1
  for (int m0 = 0; m0 < 1024; m0 += 64) {
    float aloc[8][4];
    #pragma unroll
    for (int g = 0; g < 8; ++g)
      #pragma unroll
      for (int r = 0; r < 4; ++r) aloc[g][r] = 0.f;

    // QK + mix for all 8 heads, software-pipelined K loads
    {
      const bf16* kr0 = kh + ((size_t)(b * 8)) * 1024 * 96 + (size_t)m0 * 96 + koff;
      uint4 c0 = *(const uint4*)(kr0);
      uint4 c1 = *(const uint4*)(kr0 + 32);
      uint4 c2 = *(const uint4*)(kr0 + 64);
      #pragma unroll 1
      for (int h = 0; h < 8; ++h) {
        const int hn = (h < 7) ? h + 1 : 7;
        const bf16* krn = kh + ((size_t)(b * 8 + hn)) * 1024 * 96 + (size_t)m0 * 96 + koff;
        uint4 p0 = *(const uint4*)(krn);
        uint4 p1 = *(const uint4*)(krn + 32);
        uint4 p2 = *(const uint4*)(krn + 64);
        f32x4 acc = {0.f, 0.f, 0.f, 0.f};
        acc = mfma16(qf[h][0], c0, acc);
        acc = mfma16(qf[h][1], c1, acc);
        acc = mfma16(qf[h][2], c2, acc);
        float p[4];
        #pragma unroll
        for (int r = 0; r < 4; ++r)
          p[r] = __expf(fminf(acc[r] * SCALE, 25.f)) * Linv[h][quad * 4 + r];
        #pragma unroll
        for (int g = 0; g < 8; ++g) {
          const float wm = Wm[h][g];
          #pragma unroll
          for (int r = 0; r < 4; ++r) aloc[g][r] = fmaf(p[r], wm, aloc[g][r]);
        }
        c0 = p0; c1 = p1; c2 = p2;
      }
    }
    // a_final -> Am (C layout -> LDS -> A layout)
    #pragma unroll
    for (int g = 0; g < 8; ++g) {
      const float iv = invg[g], cc = cg[g];
      #pragma unroll
      for (int r = 0; r < 4; ++r)
        Am[g][quad * 4 + r][w * 16 + l15] = __float2bfloat16(fmaf(iv, aloc[g][r], cc));
    }
    __syncthreads();

    // PV: D[n][d] += A(Am) * B(vt)
    #pragma unroll 2
    for (int g = 0; g < 8; ++g) {
      const bf16* vg = vt + ((size_t)(b * 8 + g)) * 96 * 1024;
      uint4 a0 = *(const uint4*)&Am[g][l15][quad * 8];        // ks=0
      uint4 a1 = *(const uint4*)&Am[g][l15][32 + quad * 8];   // ks=1
      {
        const bf16* vrow = vg + (size_t)(dtA * 16 + l15) * 1024 + m0 + quad * 8;
        uint4 v0 = *(const uint4*)(vrow);
        uint4 v1 = *(const uint4*)(vrow + 32);
        f32x4 acc; acc.x = accA[g][0]; acc.y = accA[g][1]; acc.z = accA[g][2]; acc.w = accA[g][3];
        acc = mfma16(a0, v0, acc);
        acc = mfma16(a1, v1, acc);
        accA[g][0] = acc.x; accA[g][1] = acc.y; accA[g][2] = acc.z; accA[g][3] = acc.w;
      }
      if ((g & 4) == gB0) {
        const int gg = g & 3;
        const bf16* vrow = vg + (size_t)(dtB * 16 + l15) * 1024 + m0 + quad * 8;
        uint4 v0 = *(const uint4*)(vrow);
        uint4 v1 = *(const uint4*)(vrow + 32);
        f32x4 acc; acc.x = accB[gg][0]; acc.y = accB[gg][1]; acc.z = accB[gg][2]; acc.w = accB[gg][3];
        acc = mfma16(a0, v0, acc);
        acc = mfma16(a1, v1, acc);
        accB[gg][0] = acc.x; accB[gg][1] = acc.y; accB[gg][2] = acc.z; accB[gg][3] = acc.w;
      }
    }
    __syncthreads();
  }

  // epilogue: X[b, n0+n, g*96 + d]
  const size_t xbase = ((size_t)(b * 1024 + n0)) * 768;
  #pragma unroll
  for (int g = 0; g < 8; ++g)
    #pragma unroll
    for (int r = 0; r < 4; ++r)
      X[xbase + (size_t)(quad * 4 + r) * 768 + g * 96 + dtA * 16 + l15] = accA[g][r];
  #pragma unroll
  for (int gg = 0; gg < 4; ++gg)
    #pragma unroll
    for (int r = 0; r < 4; ++r)
      X[xbase + (size_t)(quad * 4 + r) * 768 + (gB0 + gg) * 96 + dtB * 16 + l15] = accB[gg][r];
}

// ---------------------------------------------------------------------------
// Kernel D: out = X @ proj_w + proj_b  (8192x768)@(768x768) fp32 (unchanged)
// ---------------------------------------------------------------------------
__global__ __launch_bounds__(256) void proj_kernel(
    const float* __restrict__ X, const float* __restrict__ pw, const float* __restrict__ pb,
    float* __restrict__ out)
{
  __shared__ float Xs[64][17];
  __shared__ float Ws[16][65];
  const int t = threadIdx.x;
  const int bc = blockIdx.x % 12, br = blockIdx.x / 12;
  const int row0 = br * 64, col0 = bc * 64;
  const int tn = t >> 4, tc = t & 15;
  float acc2[4][4] = {{0.f}};

  for (int kt = 0; kt < 768; kt += 16) {
    __syncthreads();
    #pragma unroll
    for (int it = 0; it < 4; ++it) {
      const int idx = t + it * 256;
      const int r = idx >> 4, kk = idx & 15;
      Xs[r][kk] = X[(size_t)(row0 + r) * 768 + kt + kk];
    }
    #pragma unroll
    for (int it = 0; it < 4; ++it) {
      const int idx = t + it * 256;
      const int kk = idx >> 6, c = idx & 63;
      Ws[kk][c] = pw[(size_t)(kt + kk) * 768 + col0 + c];
    }
    __syncthreads();
    #pragma unroll
    for (int kk = 0; kk < 16; ++kk) {
      float a[4], bb4[4];
      #pragma unroll
      for (int i = 0; i < 4; ++i) a[i] = Xs[tn + 16 * i][kk];
      #pragma unroll
      for (int j = 0; j < 4; ++j) bb4[j] = Ws[kk][tc + 16 * j];
      #pragma unroll
      for (int i = 0; i < 4; ++i)
        #pragma unroll
        for (int j = 0; j < 4; ++j)
          acc2[i][j] = fmaf(a[i], bb4[j], acc2[i][j]);
    }
  }
  #pragma unroll
  for (int i = 0; i < 4; ++i)
    #pragma unroll
    for (int j = 0; j < 4; ++j) {
      const int c = col0 + tc + 16 * j;
      out[(size_t)(row0 + tn + 16 * i) * 768 + c] = acc2[i][j] + pb[c];
    }
}

// ---------------------------------------------------------------------------
extern "C" void kernel_launch(void* const* d_in, const int* in_sizes, int n_in,
                              void* d_out, int out_size, void* d_ws, size_t ws_size,
                              hipStream_t stream)
{
  const float* q  = (const float*)d_in[0];
  const float* k  = (const float*)d_in[1];
  const float* v  = (const float*)d_in[2];
  const float* cw = (const float*)d_in[3];
  const float* rw = (const float*)d_in[4];
  const float* rb = (const float*)d_in[5];
  const float* bg = (const float*)d_in[6];
  const float* bb = (const float*)d_in[7];
  const float* bm = (const float*)d_in[8];
  const float* bv = (const float*)d_in[9];
  const float* pw = (const float*)d_in[10];
  const float* pb = (const float*)d_in[11];
  float* out = (float*)d_out;

  char* ws = (char*)d_ws;
  // bf16 [64][1024][96] tensors = 12,582,912 B each
  bf16*  qh = (bf16*)(ws);
  bf16*  kh = (bf16*)(ws + 12582912);
  bf16*  vt = (bf16*)(ws + 25165824);             // transposed V [64][96][1024]
  float* X  = (float*)(ws + 37748736);            // 8*1024*768 fp32 = 25,165,824 B
  bf16*  vhT = (bf16*)X;                          // temp vh, dead after vtrans
  // total ws usage: 62,914,560 B (same footprint as round 3)

  conv_kernel<<<8192, 256, 0, stream>>>(q, k, v, cw, qh, kh, vhT);
  vtrans_kernel<<<1024, 256, 0, stream>>>(vhT, vt);
  attn_kernel<<<512, 256, 0, stream>>>(qh, kh, vt, rw, rb, bg, bb, bm, bv, X);
  proj_kernel<<<1536, 256, 0, stream>>>(X, pw, pb, out);
}

// Round 5
// 561.052 us; speedup vs baseline: 2.7602x; 1.1593x over previous
//
#include <hip/hip_runtime.h>
#include <hip/hip_bf16.h>
#include <stdint.h>

typedef __hip_bfloat16 bf16;
typedef __attribute__((ext_vector_type(8))) short short8;  // 8 bf16 = 4 VGPR
typedef __attribute__((ext_vector_type(4))) float f32x4;

#define DEVFN __device__ __forceinline__

// B=8, N=1024, DIM=768, HEADS=8, HEAD_DIM=96, S=16, CH=3. fp32 in/out.
constexpr float SCALE = 0.10206207261596577f;   // 96^-0.5

DEVFN short8 as_s8(uint4 u) { union { uint4 a; short8 b; } x; x.a = u; return x.b; }

DEVFN f32x4 mfma16(uint4 a, uint4 b, f32x4 c) {
  return __builtin_amdgcn_mfma_f32_16x16x32_bf16(as_s8(a), as_s8(b), c, 0, 0, 0);
}

// ---------------------------------------------------------------------------
// Kernel A: 3x3 SAME conv on (16,16,3) image view; head = y>>1,
// d = (y&1)*48 + x*3 + c.  fp32 in -> bf16 qh/kh/vh [B*H][1024][96].
// ---------------------------------------------------------------------------
__global__ __launch_bounds__(256) void conv_kernel(
    const float* __restrict__ q, const float* __restrict__ k, const float* __restrict__ v,
    const float* __restrict__ cw,
    bf16* __restrict__ qh, bf16* __restrict__ kh, bf16* __restrict__ vh)
{
  __shared__ float img[3][768];
  __shared__ float wsm[81];
  const int t = threadIdx.x;
  const size_t pos = blockIdx.x;
  const int b = blockIdx.x >> 10;
  const int n = blockIdx.x & 1023;

  {
    const float* s0 = q + pos * 768;
    const float* s1 = k + pos * 768;
    const float* s2 = v + pos * 768;
    img[0][t] = s0[t]; img[0][t + 256] = s0[t + 256]; img[0][t + 512] = s0[t + 512];
    img[1][t] = s1[t]; img[1][t + 256] = s1[t + 256]; img[1][t + 512] = s1[t + 512];
    img[2][t] = s2[t]; img[2][t + 256] = s2[t + 256]; img[2][t + 512] = s2[t + 512];
  }
  if (t < 81) wsm[t] = cw[t];
  __syncthreads();

  #pragma unroll
  for (int s3 = 0; s3 < 3; ++s3) {
    bf16* dst = (s3 == 0) ? qh : (s3 == 1) ? kh : vh;
    #pragma unroll
    for (int r = 0; r < 3; ++r) {
      const int f  = t + r * 256;
      const int co = f % 3;
      const int x  = (f / 3) & 15;
      const int y  = f / 48;
      float acc = 0.f;
      #pragma unroll
      for (int dy = 0; dy < 3; ++dy) {
        const int iy = y + dy - 1;
        if ((unsigned)iy < 16u) {
          #pragma unroll
          for (int dx = 0; dx < 3; ++dx) {
            const int ix = x + dx - 1;
            if ((unsigned)ix < 16u) {
              const int ib = iy * 48 + ix * 3;
              const int wb = (dy * 3 + dx) * 9 + co;
              acc = fmaf(img[s3][ib + 0], wsm[wb + 0], acc);
              acc = fmaf(img[s3][ib + 1], wsm[wb + 3], acc);
              acc = fmaf(img[s3][ib + 2], wsm[wb + 6], acc);
            }
          }
        }
      }
      const int head = y >> 1;
      const int d    = (y & 1) * 48 + x * 3 + co;
      dst[(((size_t)(b * 8 + head)) * 1024 + n) * 96 + d] = __float2bfloat16(acc);
    }
  }
}

// ---------------------------------------------------------------------------
// Kernel T: transpose vh [bg][1024 n][96 d] -> vt [bg][96 d][1024 n] (bf16)
// ---------------------------------------------------------------------------
__global__ __launch_bounds__(256) void vtrans_kernel(
    const bf16* __restrict__ vh, bf16* __restrict__ vt)
{
  __shared__ unsigned T[64][52];
  const int t = threadIdx.x;
  const int bg = blockIdx.x >> 4;
  const int n0 = (blockIdx.x & 15) << 6;
  const bf16* src = vh + ((size_t)bg * 1024 + n0) * 96;
  #pragma unroll
  for (int it = 0; it < 3; ++it) {
    const int i = t + it * 256;
    const int r = i / 12, j = i - r * 12;
    ((uint4*)&T[r][0])[j] = ((const uint4*)(src + (size_t)r * 96))[j];
  }
  __syncthreads();
  #pragma unroll
  for (int it = 0; it < 3; ++it) {
    const int i = t + it * 256;
    const int d = i >> 3, c = i & 7;
    unsigned wo[4];
    #pragma unroll
    for (int p = 0; p < 4; ++p) {
      const unsigned lo = T[c * 8 + p * 2    ][d >> 1];
      const unsigned hi = T[c * 8 + p * 2 + 1][d >> 1];
      const unsigned a  = (d & 1) ? (lo >> 16)          : (lo & 0xffffu);
      const unsigned bs = (d & 1) ? (hi & 0xffff0000u)  : (hi << 16);
      wo[p] = a | bs;
    }
    uint4 out4; out4.x = wo[0]; out4.y = wo[1]; out4.z = wo[2]; out4.w = wo[3];
    *(uint4*)(vt + ((size_t)bg * 96 + d) * 1024 + n0 + c * 8) = out4;
  }
}

// ---------------------------------------------------------------------------
// Kernel L: partial softmax denominators.
// Block = (b, 16 q-rows, m-chunk of 256). Wave w takes m-quadrant w of each
// 64-wide m-tile. Partial L summed into Lbuf[(b*8+h)*1024 + n] via atomicAdd.
// ---------------------------------------------------------------------------
__global__ __launch_bounds__(256) void lsum_kernel(
    const bf16* __restrict__ qh, const bf16* __restrict__ kh,
    float* __restrict__ Lbuf)
{
  const int t     = threadIdx.x;
  const int b     = blockIdx.x & 7;
  const int idx   = blockIdx.x >> 3;
  const int n0    = (idx & 63) << 4;
  const int mbase = (idx >> 6) << 8;
  const int w     = t >> 6;
  const int lane  = t & 63;
  const int l15   = lane & 15;
  const int quad  = lane >> 4;

  #pragma unroll 1
  for (int h = 0; h < 8; ++h) {
    const bf16* qrow = qh + (((size_t)(b * 8 + h)) * 1024 + n0 + l15) * 96 + quad * 8;
    const uint4 q0 = *(const uint4*)(qrow);
    const uint4 q1 = *(const uint4*)(qrow + 32);
    const uint4 q2 = *(const uint4*)(qrow + 64);
    const bf16* kbase = kh + ((size_t)(b * 8 + h)) * 1024 * 96
                        + (size_t)(mbase + w * 16 + l15) * 96 + quad * 8;
    float lac[4] = {0.f, 0.f, 0.f, 0.f};
    uint4 c0 = *(const uint4*)(kbase);
    uint4 c1 = *(const uint4*)(kbase + 32);
    uint4 c2 = *(const uint4*)(kbase + 64);
    #pragma unroll 1
    for (int i = 0; i < 4; ++i) {
      const int inext = (i < 3) ? i + 1 : 3;
      const bf16* kn = kbase + (size_t)(inext * 64) * 96;
      uint4 p0 = *(const uint4*)(kn);
      uint4 p1 = *(const uint4*)(kn + 32);
      uint4 p2 = *(const uint4*)(kn + 64);
      f32x4 acc = {0.f, 0.f, 0.f, 0.f};
      acc = mfma16(q0, c0, acc);
      acc = mfma16(q1, c1, acc);
      acc = mfma16(q2, c2, acc);
      #pragma unroll
      for (int r = 0; r < 4; ++r)
        lac[r] += __expf(fminf(acc[r] * SCALE, 25.f));
      c0 = p0; c1 = p1; c2 = p2;
    }
    #pragma unroll
    for (int off = 1; off < 16; off <<= 1) {
      #pragma unroll
      for (int r = 0; r < 4; ++r) lac[r] += __shfl_xor(lac[r], off);
    }
    if (l15 == 0) {
      #pragma unroll
      for (int r = 0; r < 4; ++r)
        atomicAdd(&Lbuf[(((b * 8 + h)) << 10) + n0 + quad * 4 + r], lac[r]);
    }
  }
}

// ---------------------------------------------------------------------------
// Kernel C: m-chunked MFMA attention. Block = (b, 16 q-rows, m-chunk 256).
// p = exp(s)/L -> a_final = inv_g*sum_h W[h,g] p_h + c_g -> PV partial,
// atomicAdd into zero-initialized fp32 X. Exact under m-split since a_final
// is applied per (n,m).
// ---------------------------------------------------------------------------
__global__ __launch_bounds__(256, 4) void attn2_kernel(
    const bf16* __restrict__ qh, const bf16* __restrict__ kh, const bf16* __restrict__ vt,
    const float* __restrict__ Lbuf,
    const float* __restrict__ rw, const float* __restrict__ rb,
    const float* __restrict__ bng, const float* __restrict__ bnb,
    const float* __restrict__ bnm, const float* __restrict__ bnv,
    float* __restrict__ X)
{
  __shared__ bf16 Am[8][16][72];            // stride 72 elems = 144B (16B-aligned)
  __shared__ float Linv[8][16];
  __shared__ float Wm[8][8];
  __shared__ float invg[8], cg[8];

  const int t     = threadIdx.x;
  const int b     = blockIdx.x & 7;         // XCD swizzle
  const int idx   = blockIdx.x >> 3;
  const int n0    = (idx & 63) << 4;
  const int mbase = (idx >> 6) << 8;
  const int w     = t >> 6;
  const int lane  = t & 63;
  const int l15   = lane & 15;
  const int quad  = lane >> 4;

  if (t < 64) Wm[t >> 3][t & 7] = rw[t];
  if (t < 8) {
    const float iv = bng[t] * rsqrtf(bnv[t] + 1e-3f);
    invg[t] = iv;
    cg[t]   = iv * (rb[t] - bnm[t]) + bnb[t];
  }
  if (t < 128) {
    const int h = t >> 4, nn = t & 15;
    Linv[h][nn] = 1.f / Lbuf[((b * 8 + h) << 10) + n0 + nn];
  }
  __syncthreads();

  const int dtA = w;
  const int dtB = 4 + (w >> 1);
  const int gB0 = (w & 1) * 4;

  float accA[8][4], accB[4][4];
  #pragma unroll
  for (int g = 0; g < 8; ++g)
    #pragma unroll
    for (int r = 0; r < 4; ++r) accA[g][r] = 0.f;
  #pragma unroll
  for (int g = 0; g < 4; ++g)
    #pragma unroll
    for (int r = 0; r < 4; ++r) accB[g][r] = 0.f;

  const size_t koff = (size_t)(w * 16 + l15) * 96 + quad * 8;

  #pragma unroll 1
  for (int mi = 0; mi < 4; ++mi) {
    const int m0 = mbase + mi * 64;
    float aloc[8][4];
    #pragma unroll
    for (int g = 0; g < 8; ++g)
      #pragma unroll
      for (int r = 0; r < 4; ++r) aloc[g][r] = 0.f;

    {
      const bf16* kr0 = kh + ((size_t)(b * 8)) * 1024 * 96 + (size_t)m0 * 96 + koff;
      uint4 c0 = *(const uint4*)(kr0);
      uint4 c1 = *(const uint4*)(kr0 + 32);
      uint4 c2 = *(const uint4*)(kr0 + 64);
      #pragma unroll 1
      for (int h = 0; h < 8; ++h) {
        const int hn = (h < 7) ? h + 1 : 7;
        const bf16* krn = kh + ((size_t)(b * 8 + hn)) * 1024 * 96 + (size_t)m0 * 96 + koff;
        uint4 p0 = *(const uint4*)(krn);
        uint4 p1 = *(const uint4*)(krn + 32);
        uint4 p2 = *(const uint4*)(krn + 64);
        const bf16* qrow = qh + (((size_t)(b * 8 + h)) * 1024 + n0 + l15) * 96 + quad * 8;
        const uint4 q0 = *(const uint4*)(qrow);
        const uint4 q1 = *(const uint4*)(qrow + 32);
        const uint4 q2 = *(const uint4*)(qrow + 64);
        f32x4 acc = {0.f, 0.f, 0.f, 0.f};
        acc = mfma16(q0, c0, acc);
        acc = mfma16(q1, c1, acc);
        acc = mfma16(q2, c2, acc);
        float p[4];
        #pragma unroll
        for (int r = 0; r < 4; ++r)
          p[r] = __expf(fminf(acc[r] * SCALE, 25.f)) * Linv[h][quad * 4 + r];
        #pragma unroll
        for (int g = 0; g < 8; ++g) {
          const float wm = Wm[h][g];
          #pragma unroll
          for (int r = 0; r < 4; ++r) aloc[g][r] = fmaf(p[r], wm, aloc[g][r]);
        }
        c0 = p0; c1 = p1; c2 = p2;
      }
    }
    #pragma unroll
    for (int g = 0; g < 8; ++g) {
      const float iv = invg[g], cc = cg[g];
      #pragma unroll
      for (int r = 0; r < 4; ++r)
        Am[g][quad * 4 + r][w * 16 + l15] = __float2bfloat16(fmaf(iv, aloc[g][r], cc));
    }
    __syncthreads();

    #pragma unroll 2
    for (int g = 0; g < 8; ++g) {
      const bf16* vg = vt + ((size_t)(b * 8 + g)) * 96 * 1024;
      uint4 a0 = *(const uint4*)&Am[g][l15][quad * 8];
      uint4 a1 = *(const uint4*)&Am[g][l15][32 + quad * 8];
      {
        const bf16* vrow = vg + (size_t)(dtA * 16 + l15) * 1024 + m0 + quad * 8;
        uint4 v0 = *(const uint4*)(vrow);
        uint4 v1 = *(const uint4*)(vrow + 32);
        f32x4 acc; acc.x = accA[g][0]; acc.y = accA[g][1]; acc.z = accA[g][2]; acc.w = accA[g][3];
        acc = mfma16(a0, v0, acc);
        acc = mfma16(a1, v1, acc);
        accA[g][0] = acc.x; accA[g][1] = acc.y; accA[g][2] = acc.z; accA[g][3] = acc.w;
      }
      if ((g & 4) == gB0) {
        const int gg = g & 3;
        const bf16* vrow = vg + (size_t)(dtB * 16 + l15) * 1024 + m0 + quad * 8;
        uint4 v0 = *(const uint4*)(vrow);
        uint4 v1 = *(const uint4*)(vrow + 32);
        f32x4 acc; acc.x = accB[gg][0]; acc.y = accB[gg][1]; acc.z = accB[gg][2]; acc.w = accB[gg][3];
        acc = mfma16(a0, v0, acc);
        acc = mfma16(a1, v1, acc);
        accB[gg][0] = acc.x; accB[gg][1] = acc.y; accB[gg][2] = acc.z; accB[gg][3] = acc.w;
      }
    }
    __syncthreads();
  }

  const size_t xbase = ((size_t)(b * 1024 + n0)) * 768;
  #pragma unroll
  for (int g = 0; g < 8; ++g)
    #pragma unroll
    for (int r = 0; r < 4; ++r)
      atomicAdd(&X[xbase + (size_t)(quad * 4 + r) * 768 + g * 96 + dtA * 16 + l15], accA[g][r]);
  #pragma unroll
  for (int gg = 0; gg < 4; ++gg)
    #pragma unroll
    for (int r = 0; r < 4; ++r)
      atomicAdd(&X[xbase + (size_t)(quad * 4 + r) * 768 + (gB0 + gg) * 96 + dtB * 16 + l15], accB[gg][r]);
}

// ---------------------------------------------------------------------------
// Kernel S1: split X (fp32) -> Xhi/Xlo (bf16), exact to ~1.6e-5 rel.
// ---------------------------------------------------------------------------
__global__ __launch_bounds__(256) void xsplit_kernel(
    const float* __restrict__ X, ushort* __restrict__ Xhi, ushort* __restrict__ Xlo)
{
  const size_t i = ((size_t)blockIdx.x * 256 + threadIdx.x) * 4;
  const float4 x = *(const float4*)(X + i);
  ushort h[4], l[4];
  const float xs[4] = {x.x, x.y, x.z, x.w};
  #pragma unroll
  for (int j = 0; j < 4; ++j) {
    const float fhi = __bfloat162float(__float2bfloat16(xs[j]));
    h[j] = (ushort)(__float_as_uint(fhi) >> 16);
    const float flo = xs[j] - fhi;
    l[j] = (ushort)(__float_as_uint(__bfloat162float(__float2bfloat16(flo))) >> 16);
  }
  ushort4 hv; hv.x = h[0]; hv.y = h[1]; hv.z = h[2]; hv.w = h[3];
  ushort4 lv; lv.x = l[0]; lv.y = l[1]; lv.z = l[2]; lv.w = l[3];
  *(ushort4*)(Xhi + i) = hv;
  *(ushort4*)(Xlo + i) = lv;
}

// ---------------------------------------------------------------------------
// Kernel S2: transpose + split proj_w: WT[n][k] = W[k][n] as hi/lo bf16.
// ---------------------------------------------------------------------------
__global__ __launch_bounds__(256) void wsplit_kernel(
    const float* __restrict__ pw, ushort* __restrict__ WhT, ushort* __restrict__ WlT)
{
  __shared__ float T[32][33];
  const int t  = threadIdx.x;
  const int kt = (blockIdx.x % 24) * 32;
  const int nt = (blockIdx.x / 24) * 32;
  #pragma unroll
  for (int it = 0; it < 4; ++it) {
    const int i = t + it * 256;
    const int r = i >> 5, c = i & 31;
    T[r][c] = pw[(size_t)(kt + r) * 768 + nt + c];
  }
  __syncthreads();
  #pragma unroll
  for (int it = 0; it < 4; ++it) {
    const int i = t + it * 256;
    const int r = i >> 5, c = i & 31;      // r = n-local, c = k-local
    const float x = T[c][r];               // W[kt+c][nt+r]
    const float fhi = __bfloat162float(__float2bfloat16(x));
    const float flo = x - fhi;
    WhT[(size_t)(nt + r) * 768 + kt + c] = (ushort)(__float_as_uint(fhi) >> 16);
    WlT[(size_t)(nt + r) * 768 + kt + c] =
        (ushort)(__float_as_uint(__bfloat162float(__float2bfloat16(flo))) >> 16);
  }
}

// ---------------------------------------------------------------------------
// Kernel D: out = X @ proj_w + proj_b via 3-term split-bf16 MFMA:
// XhiWhi + XloWhi + XhiWlo. 64x64 block tile, BK=64, wave = 32x32.
// ---------------------------------------------------------------------------
__global__ __launch_bounds__(256) void proj2_kernel(
    const ushort* __restrict__ Xhi, const ushort* __restrict__ Xlo,
    const ushort* __restrict__ WhT, const ushort* __restrict__ WlT,
    const float* __restrict__ pb, float* __restrict__ out)
{
  __shared__ unsigned Ah[64][36], Al[64][36], Bh[64][36], Bl[64][36];
  const int t    = threadIdx.x;
  const int bc   = blockIdx.x % 12, br = blockIdx.x / 12;
  const int row0 = br * 64, col0 = bc * 64;
  const int w    = t >> 6;
  const int lane = t & 63;
  const int l15  = lane & 15;
  const int quad = lane >> 4;
  const int wr   = w >> 1, wc = w & 1;

  f32x4 acc[2][2];
  #pragma unroll
  for (int i = 0; i < 2; ++i)
    #pragma unroll
    for (int j = 0; j < 2; ++j) acc[i][j] = (f32x4){0.f, 0.f, 0.f, 0.f};

  for (int kt = 0; kt < 768; kt += 64) {
    __syncthreads();
    #pragma unroll
    for (int it = 0; it < 2; ++it) {
      const int i = t + it * 256;          // 0..511
      const int r = i >> 3, j = i & 7;
      ((uint4*)&Ah[r][0])[j] = *(const uint4*)(Xhi + (size_t)(row0 + r) * 768 + kt + j * 8);
      ((uint4*)&Al[r][0])[j] = *(const uint4*)(Xlo + (size_t)(row0 + r) * 768 + kt + j * 8);
      ((uint4*)&Bh[r][0])[j] = *(const uint4*)(WhT + (size_t)(col0 + r) * 768 + kt + j * 8);
      ((uint4*)&Bl[r][0])[j] = *(const uint4*)(WlT + (size_t)(col0 + r) * 768 + kt + j * 8);
    }
    __syncthreads();
    #pragma unroll
    for (int ks = 0; ks < 2; ++ks) {
      const int ko = ks * 16 + quad * 4;   // unsigned-word offset within row
      uint4 ah[2], al[2], bh[2], bl[2];
      #pragma unroll
      for (int i = 0; i < 2; ++i) {
        ah[i] = *(const uint4*)&Ah[wr * 32 + i * 16 + l15][ko];
        al[i] = *(const uint4*)&Al[wr * 32 + i * 16 + l15][ko];
      }
      #pragma unroll
      for (int j = 0; j < 2; ++j) {
        bh[j] = *(const uint4*)&Bh[wc * 32 + j * 16 + l15][ko];
        bl[j] = *(const uint4*)&Bl[wc * 32 + j * 16 + l15][ko];
      }
      #pragma unroll
      for (int i = 0; i < 2; ++i)
        #pragma unroll
        for (int j = 0; j < 2; ++j) {
          acc[i][j] = mfma16(ah[i], bh[j], acc[i][j]);
          acc[i][j] = mfma16(al[i], bh[j], acc[i][j]);
          acc[i][j] = mfma16(ah[i], bl[j], acc[i][j]);
        }
    }
  }

  #pragma unroll
  for (int i = 0; i < 2; ++i)
    #pragma unroll
    for (int j = 0; j < 2; ++j) {
      const int col = col0 + wc * 32 + j * 16 + l15;
      const float bias = pb[col];
      #pragma unroll
      for (int r = 0; r < 4; ++r)
        out[(size_t)(row0 + wr * 32 + i * 16 + quad * 4 + r) * 768 + col] = acc[i][j][r] + bias;
    }
}

// ---------------------------------------------------------------------------
extern "C" void kernel_launch(void* const* d_in, const int* in_sizes, int n_in,
                              void* d_out, int out_size, void* d_ws, size_t ws_size,
                              hipStream_t stream)
{
  const float* q  = (const float*)d_in[0];
  const float* k  = (const float*)d_in[1];
  const float* v  = (const float*)d_in[2];
  const float* cw = (const float*)d_in[3];
  const float* rw = (const float*)d_in[4];
  const float* rb = (const float*)d_in[5];
  const float* bg = (const float*)d_in[6];
  const float* bb = (const float*)d_in[7];
  const float* bm = (const float*)d_in[8];
  const float* bv = (const float*)d_in[9];
  const float* pw = (const float*)d_in[10];
  const float* pb = (const float*)d_in[11];
  float* out = (float*)d_out;

  char* ws = (char*)d_ws;
  bf16*  qh = (bf16*)(ws);                         // 12,582,912 B
  bf16*  kh = (bf16*)(ws + 12582912);              // 12,582,912 B
  bf16*  vt = (bf16*)(ws + 25165824);              // 12,582,912 B (V^T)
  float* X  = (float*)(ws + 37748736);             // 25,165,824 B (fp32 attn out)
  bf16*  vhT = (bf16*)X;                           // temp vh, dead after vtrans
  // Aliases (live only after attn2):
  ushort* Xhi = (ushort*)qh;                       // 12,582,912 B
  ushort* Xlo = (ushort*)kh;                       // 12,582,912 B
  ushort* WhT = (ushort*)vt;                       // 1,179,648 B
  ushort* WlT = (ushort*)((char*)vt + 1179648);    // 1,179,648 B
  // Lbuf scratch lives in d_out's head; proj2 overwrites all of d_out later.
  float* Lbuf = (float*)d_out;                     // 262,144 B

  hipMemsetAsync(Lbuf, 0, 262144, stream);
  conv_kernel<<<8192, 256, 0, stream>>>(q, k, v, cw, qh, kh, vhT);
  vtrans_kernel<<<1024, 256, 0, stream>>>(vhT, vt);
  hipMemsetAsync(X, 0, 25165824, stream);
  lsum_kernel<<<2048, 256, 0, stream>>>(qh, kh, Lbuf);
  attn2_kernel<<<2048, 256, 0, stream>>>(qh, kh, vt, Lbuf, rw, rb, bg, bb, bm, bv, X);
  xsplit_kernel<<<6144, 256, 0, stream>>>(X, Xhi, Xlo);
  wsplit_kernel<<<576, 256, 0, stream>>>(pw, WhT, WlT);
  proj2_kernel<<<1536, 256, 0, stream>>>(Xhi, Xlo, WhT, WlT, pb, out);
}

// Round 6
// 531.873 us; speedup vs baseline: 2.9116x; 1.0549x over previous
//
#include <hip/hip_runtime.h>
#include <hip/hip_bf16.h>
#include <stdint.h>

typedef __hip_bfloat16 bf16;
typedef __attribute__((ext_vector_type(8))) short short8;  // 8 bf16 = 4 VGPR
typedef __attribute__((ext_vector_type(4))) float f32x4;

#define DEVFN __device__ __forceinline__

// B=8, N=1024, DIM=768, HEADS=8, HEAD_DIM=96, S=16, CH=3. fp32 in/out.
constexpr float SCALE = 0.10206207261596577f;   // 96^-0.5

DEVFN short8 as_s8(uint4 u) { union { uint4 a; short8 b; } x; x.a = u; return x.b; }

DEVFN f32x4 mfma16(uint4 a, uint4 b, f32x4 c) {
  return __builtin_amdgcn_mfma_f32_16x16x32_bf16(as_s8(a), as_s8(b), c, 0, 0, 0);
}

DEVFN uint4 ldg4(const bf16* p) { return *(const uint4*)p; }

// ---------------------------------------------------------------------------
// Kernel A: 3x3 SAME conv on (16,16,3) image view; head = y>>1,
// d = (y&1)*48 + x*3 + c.  fp32 in -> bf16 qh/kh/vh [B*H][1024][96].
// One thread per (y,x); computes all 3 co (shares the 27 input reads).
// ---------------------------------------------------------------------------
__global__ __launch_bounds__(256) void conv_kernel(
    const float* __restrict__ q, const float* __restrict__ k, const float* __restrict__ v,
    const float* __restrict__ cw,
    bf16* __restrict__ qh, bf16* __restrict__ kh, bf16* __restrict__ vh)
{
  __shared__ float img[3][768];
  __shared__ float wsm[81];
  const int t = threadIdx.x;
  const size_t pos = blockIdx.x;
  const int b = blockIdx.x >> 10;
  const int n = blockIdx.x & 1023;

  {
    const float* s0 = q + pos * 768;
    const float* s1 = k + pos * 768;
    const float* s2 = v + pos * 768;
    img[0][t] = s0[t]; img[0][t + 256] = s0[t + 256]; img[0][t + 512] = s0[t + 512];
    img[1][t] = s1[t]; img[1][t + 256] = s1[t + 256]; img[1][t + 512] = s1[t + 512];
    img[2][t] = s2[t]; img[2][t + 256] = s2[t + 256]; img[2][t + 512] = s2[t + 512];
  }
  if (t < 81) wsm[t] = cw[t];
  __syncthreads();

  const int x    = t & 15;
  const int y    = t >> 4;
  const int head = y >> 1;
  const int d0   = (y & 1) * 48 + x * 3;
  const size_t obase = (((size_t)(b * 8 + head)) * 1024 + n) * 96 + d0;

  #pragma unroll
  for (int s3 = 0; s3 < 3; ++s3) {
    float a0 = 0.f, a1 = 0.f, a2 = 0.f;
    #pragma unroll
    for (int dy = 0; dy < 3; ++dy) {
      const int iy = y + dy - 1;
      if ((unsigned)iy < 16u) {
        #pragma unroll
        for (int dx = 0; dx < 3; ++dx) {
          const int ix = x + dx - 1;
          if ((unsigned)ix < 16u) {
            const int ib = iy * 48 + ix * 3;
            const int wb = (dy * 3 + dx) * 9;
            #pragma unroll
            for (int ci = 0; ci < 3; ++ci) {
              const float val = img[s3][ib + ci];
              a0 = fmaf(val, wsm[wb + ci * 3 + 0], a0);
              a1 = fmaf(val, wsm[wb + ci * 3 + 1], a1);
              a2 = fmaf(val, wsm[wb + ci * 3 + 2], a2);
            }
          }
        }
      }
    }
    bf16* dst = (s3 == 0) ? qh : (s3 == 1) ? kh : vh;
    dst[obase]     = __float2bfloat16(a0);
    dst[obase + 1] = __float2bfloat16(a1);
    dst[obase + 2] = __float2bfloat16(a2);
  }
}

// ---------------------------------------------------------------------------
// Kernel T: transpose vh [bg][1024 n][96 d] -> vt [bg][96 d][1024 n] (bf16)
// ---------------------------------------------------------------------------
__global__ __launch_bounds__(256) void vtrans_kernel(
    const bf16* __restrict__ vh, bf16* __restrict__ vt)
{
  __shared__ unsigned T[64][52];
  const int t = threadIdx.x;
  const int bg = blockIdx.x >> 4;
  const int n0 = (blockIdx.x & 15) << 6;
  const bf16* src = vh + ((size_t)bg * 1024 + n0) * 96;
  #pragma unroll
  for (int it = 0; it < 3; ++it) {
    const int i = t + it * 256;
    const int r = i / 12, j = i - r * 12;
    ((uint4*)&T[r][0])[j] = ((const uint4*)(src + (size_t)r * 96))[j];
  }
  __syncthreads();
  #pragma unroll
  for (int it = 0; it < 3; ++it) {
    const int i = t + it * 256;
    const int d = i >> 3, c = i & 7;
    unsigned wo[4];
    #pragma unroll
    for (int p = 0; p < 4; ++p) {
      const unsigned lo = T[c * 8 + p * 2    ][d >> 1];
      const unsigned hi = T[c * 8 + p * 2 + 1][d >> 1];
      const unsigned a  = (d & 1) ? (lo >> 16)          : (lo & 0xffffu);
      const unsigned bs = (d & 1) ? (hi & 0xffff0000u)  : (hi << 16);
      wo[p] = a | bs;
    }
    uint4 out4; out4.x = wo[0]; out4.y = wo[1]; out4.z = wo[2]; out4.w = wo[3];
    *(uint4*)(vt + ((size_t)bg * 96 + d) * 1024 + n0 + c * 8) = out4;
  }
}

// ---------------------------------------------------------------------------
// Kernel L: partial softmax denominators (no-max softmax, s clamped at 25).
// Block = (b, 16 q-rows, m-chunk of 256); wave w = m-quadrant w of each
// 64-tile. Q and K are 1-deep software-pipelined so no serial load stalls.
// ---------------------------------------------------------------------------
__global__ __launch_bounds__(256, 6) void lsum_kernel(
    const bf16* __restrict__ qh, const bf16* __restrict__ kh,
    float* __restrict__ Lbuf)
{
  const int t     = threadIdx.x;
  const int b     = blockIdx.x & 7;
  const int idx   = blockIdx.x >> 3;
  const int n0    = (idx & 63) << 4;
  const int mbase = (idx >> 6) << 8;
  const int w     = t >> 6;
  const int lane  = t & 63;
  const int l15   = lane & 15;
  const int quad  = lane >> 4;

  const size_t koff = (size_t)(mbase + w * 16 + l15) * 96 + quad * 8;
  const bf16* kbb = kh + (size_t)(b * 8) * 98304;

  #define QROW(h) (qh + (((size_t)(b * 8 + (h))) * 1024 + n0 + l15) * 96 + quad * 8)

  const bf16* qr0 = QROW(0);
  uint4 qc0 = ldg4(qr0), qc1 = ldg4(qr0 + 32), qc2 = ldg4(qr0 + 64);
  const bf16* kr0 = kbb + koff;
  uint4 kc0 = ldg4(kr0), kc1 = ldg4(kr0 + 32), kc2 = ldg4(kr0 + 64);

  #pragma unroll 1
  for (int h = 0; h < 8; ++h) {
    const int hn = (h < 7) ? h + 1 : 0;
    const bf16* qr = QROW(hn);
    uint4 qn0 = ldg4(qr), qn1 = ldg4(qr + 32), qn2 = ldg4(qr + 64);
    float lac[4] = {0.f, 0.f, 0.f, 0.f};
    #pragma unroll 1
    for (int i = 0; i < 4; ++i) {
      const int h2 = (i < 3) ? h : hn;
      const int i2 = (i < 3) ? i + 1 : 0;
      const bf16* kr = kbb + (size_t)h2 * 98304 + (size_t)(i2 * 64) * 96 + koff;
      uint4 kp0 = ldg4(kr), kp1 = ldg4(kr + 32), kp2 = ldg4(kr + 64);
      f32x4 acc = {0.f, 0.f, 0.f, 0.f};
      acc = mfma16(qc0, kc0, acc);
      acc = mfma16(qc1, kc1, acc);
      acc = mfma16(qc2, kc2, acc);
      #pragma unroll
      for (int r = 0; r < 4; ++r)
        lac[r] += __expf(fminf(acc[r] * SCALE, 25.f));
      kc0 = kp0; kc1 = kp1; kc2 = kp2;
    }
    #pragma unroll
    for (int off = 1; off < 16; off <<= 1) {
      #pragma unroll
      for (int r = 0; r < 4; ++r) lac[r] += __shfl_xor(lac[r], off);
    }
    if (l15 == 0) {
      #pragma unroll
      for (int r = 0; r < 4; ++r)
        atomicAdd(&Lbuf[((b * 8 + h) << 10) + n0 + quad * 4 + r], lac[r]);
    }
    qc0 = qn0; qc1 = qn1; qc2 = qn2;
  }
}

// ---------------------------------------------------------------------------
// Kernel C: m-chunked MFMA attention with full 1-deep pipelining on Q, K, V.
// p = exp(s)/L -> a_final = inv_g*sum_h W[h,g] p_h + c_g -> PV partial,
// atomicAdd into zero-initialized fp32 X.
// ---------------------------------------------------------------------------
__global__ __launch_bounds__(256, 3) void attn2_kernel(
    const bf16* __restrict__ qh, const bf16* __restrict__ kh, const bf16* __restrict__ vt,
    const float* __restrict__ Lbuf,
    const float* __restrict__ rw, const float* __restrict__ rb,
    const float* __restrict__ bng, const float* __restrict__ bnb,
    const float* __restrict__ bnm, const float* __restrict__ bnv,
    float* __restrict__ X)
{
  __shared__ bf16 Am[8][16][72];
  __shared__ float Linv[8][16];
  __shared__ float Wm[8][8];
  __shared__ float invg[8], cg[8];

  const int t     = threadIdx.x;
  const int b     = blockIdx.x & 7;         // XCD swizzle
  const int idx   = blockIdx.x >> 3;
  const int n0    = (idx & 63) << 4;
  const int mbase = (idx >> 6) << 8;
  const int w     = t >> 6;
  const int lane  = t & 63;
  const int l15   = lane & 15;
  const int quad  = lane >> 4;

  const size_t koff = (size_t)(w * 16 + l15) * 96 + quad * 8;
  const bf16* kbb = kh + (size_t)(b * 8) * 98304;

  // issue first Q/K/V loads before any LDS setup (pure global, no deps)
  const bf16* qrI = QROW(0);
  uint4 qc0 = ldg4(qrI), qc1 = ldg4(qrI + 32), qc2 = ldg4(qrI + 64);
  const bf16* krI = kbb + (size_t)mbase * 96 + koff;
  uint4 kc0 = ldg4(krI), kc1 = ldg4(krI + 32), kc2 = ldg4(krI + 64);
  const int dtA = w;
  const int dtB = 4 + (w >> 1);
  const int gB0 = (w & 1) * 4;
  const bf16* vrI = vt + (((size_t)(b * 8)) * 96 + dtA * 16 + l15) * 1024 + mbase + quad * 8;
  uint4 vc0 = ldg4(vrI), vc1 = ldg4(vrI + 32);

  if (t < 64) Wm[t >> 3][t & 7] = rw[t];
  if (t < 8) {
    const float iv = bng[t] * rsqrtf(bnv[t] + 1e-3f);
    invg[t] = iv;
    cg[t]   = iv * (rb[t] - bnm[t]) + bnb[t];
  }
  if (t < 128) {
    const int h = t >> 4, nn = t & 15;
    Linv[h][nn] = 1.f / Lbuf[((b * 8 + h) << 10) + n0 + nn];
  }
  __syncthreads();

  float accA[8][4], accB[4][4];
  #pragma unroll
  for (int g = 0; g < 8; ++g)
    #pragma unroll
    for (int r = 0; r < 4; ++r) accA[g][r] = 0.f;
  #pragma unroll
  for (int g = 0; g < 4; ++g)
    #pragma unroll
    for (int r = 0; r < 4; ++r) accB[g][r] = 0.f;

  #pragma unroll 1
  for (int mi = 0; mi < 4; ++mi) {
    const int m0 = mbase + mi * 64;
    float aloc[8][4];
    #pragma unroll
    for (int g = 0; g < 8; ++g)
      #pragma unroll
      for (int r = 0; r < 4; ++r) aloc[g][r] = 0.f;

    // ---- QK + head-mix, Q/K 1-deep pipelined ----
    #pragma unroll 1
    for (int h = 0; h < 8; ++h) {
      const int hn = (h < 7) ? h + 1 : 0;
      const int mn = (h < 7) ? m0 : ((mi < 3) ? m0 + 64 : m0);
      const bf16* kr = kbb + (size_t)hn * 98304 + (size_t)mn * 96 + koff;
      uint4 kp0 = ldg4(kr), kp1 = ldg4(kr + 32), kp2 = ldg4(kr + 64);
      const bf16* qr = QROW(hn);
      uint4 qn0 = ldg4(qr), qn1 = ldg4(qr + 32), qn2 = ldg4(qr + 64);

      f32x4 acc = {0.f, 0.f, 0.f, 0.f};
      acc = mfma16(qc0, kc0, acc);
      acc = mfma16(qc1, kc1, acc);
      acc = mfma16(qc2, kc2, acc);
      const f32x4 li  = *(const f32x4*)&Linv[h][quad * 4];
      const f32x4 wlo = *(const f32x4*)&Wm[h][0];
      const f32x4 whi = *(const f32x4*)&Wm[h][4];
      float p[4];
      #pragma unroll
      for (int r = 0; r < 4; ++r)
        p[r] = __expf(fminf(acc[r] * SCALE, 25.f)) * li[r];
      #pragma unroll
      for (int g = 0; g < 4; ++g)
        #pragma unroll
        for (int r = 0; r < 4; ++r) {
          aloc[g][r]     = fmaf(p[r], wlo[g], aloc[g][r]);
          aloc[g + 4][r] = fmaf(p[r], whi[g], aloc[g + 4][r]);
        }
      qc0 = qn0; qc1 = qn1; qc2 = qn2;
      kc0 = kp0; kc1 = kp1; kc2 = kp2;
    }

    // ---- a_final -> Am (C layout -> LDS -> A layout) ----
    #pragma unroll
    for (int g = 0; g < 8; ++g) {
      const float iv = invg[g], cc = cg[g];
      #pragma unroll
      for (int r = 0; r < 4; ++r)
        Am[g][quad * 4 + r][w * 16 + l15] = __float2bfloat16(fmaf(iv, aloc[g][r], cc));
    }
    __syncthreads();

    // ---- PV phase A: d-tile dtA, all 8 g; V 1-deep pipelined ----
    #pragma unroll 1
    for (int g = 0; g < 8; ++g) {
      const int gn  = (g < 7) ? g + 1 : gB0;
      const int dtn = (g < 7) ? dtA : dtB;
      const bf16* vr = vt + (((size_t)(b * 8 + gn)) * 96 + dtn * 16 + l15) * 1024 + m0 + quad * 8;
      uint4 vn0 = ldg4(vr), vn1 = ldg4(vr + 32);
      const uint4 a0 = *(const uint4*)&Am[g][l15][quad * 8];
      const uint4 a1 = *(const uint4*)&Am[g][l15][32 + quad * 8];
      f32x4 acc; acc.x = accA[g][0]; acc.y = accA[g][1]; acc.z = accA[g][2]; acc.w = accA[g][3];
      acc = mfma16(a0, vc0, acc);
      acc = mfma16(a1, vc1, acc);
      accA[g][0] = acc.x; accA[g][1] = acc.y; accA[g][2] = acc.z; accA[g][3] = acc.w;
      vc0 = vn0; vc1 = vn1;
    }
    // ---- PV phase B: d-tile dtB, 4 g; tail prefetches next mi's first V ----
    #pragma unroll 1
    for (int gg = 0; gg < 4; ++gg) {
      const int gn  = (gg < 3) ? gB0 + gg + 1 : 0;
      const int dtn = (gg < 3) ? dtB : dtA;
      const int mn  = (gg < 3) ? m0 : ((mi < 3) ? m0 + 64 : m0);
      const bf16* vr = vt + (((size_t)(b * 8 + gn)) * 96 + dtn * 16 + l15) * 1024 + mn + quad * 8;
      uint4 vn0 = ldg4(vr), vn1 = ldg4(vr + 32);
      const int g = gB0 + gg;
      const uint4 a0 = *(const uint4*)&Am[g][l15][quad * 8];
      const uint4 a1 = *(const uint4*)&Am[g][l15][32 + quad * 8];
      f32x4 acc; acc.x = accB[gg][0]; acc.y = accB[gg][1]; acc.z = accB[gg][2]; acc.w = accB[gg][3];
      acc = mfma16(a0, vc0, acc);
      acc = mfma16(a1, vc1, acc);
      accB[gg][0] = acc.x; accB[gg][1] = acc.y; accB[gg][2] = acc.z; accB[gg][3] = acc.w;
      vc0 = vn0; vc1 = vn1;
    }
    __syncthreads();
  }

  const size_t xbase = ((size_t)(b * 1024 + n0)) * 768;
  #pragma unroll
  for (int g = 0; g < 8; ++g)
    #pragma unroll
    for (int r = 0; r < 4; ++r)
      atomicAdd(&X[xbase + (size_t)(quad * 4 + r) * 768 + g * 96 + dtA * 16 + l15], accA[g][r]);
  #pragma unroll
  for (int gg = 0; gg < 4; ++gg)
    #pragma unroll
    for (int r = 0; r < 4; ++r)
      atomicAdd(&X[xbase + (size_t)(quad * 4 + r) * 768 + (gB0 + gg) * 96 + dtB * 16 + l15], accB[gg][r]);
}

// ---------------------------------------------------------------------------
// Kernel S2: transpose + split proj_w: WT[n][k] = W[k][n] as hi/lo bf16.
// ---------------------------------------------------------------------------
__global__ __launch_bounds__(256) void wsplit_kernel(
    const float* __restrict__ pw, ushort* __restrict__ WhT, ushort* __restrict__ WlT)
{
  __shared__ float T[32][33];
  const int t  = threadIdx.x;
  const int kt = (blockIdx.x % 24) * 32;
  const int nt = (blockIdx.x / 24) * 32;
  #pragma unroll
  for (int it = 0; it < 4; ++it) {
    const int i = t + it * 256;
    const int r = i >> 5, c = i & 31;
    T[r][c] = pw[(size_t)(kt + r) * 768 + nt + c];
  }
  __syncthreads();
  #pragma unroll
  for (int it = 0; it < 4; ++it) {
    const int i = t + it * 256;
    const int r = i >> 5, c = i & 31;
    const float x = T[c][r];
    const float fhi = __bfloat162float(__float2bfloat16(x));
    const float flo = x - fhi;
    WhT[(size_t)(nt + r) * 768 + kt + c] = (ushort)(__float_as_uint(fhi) >> 16);
    WlT[(size_t)(nt + r) * 768 + kt + c] =
        (ushort)(__float_as_uint(__bfloat162float(__float2bfloat16(flo))) >> 16);
  }
}

DEVFN void split2(float f0, float f1, unsigned& hw, unsigned& lw) {
  const float h0 = __bfloat162float(__float2bfloat16(f0));
  const float h1 = __bfloat162float(__float2bfloat16(f1));
  hw = (__float_as_uint(h0) >> 16) | (__float_as_uint(h1) & 0xffff0000u);
  const unsigned l0 = __float_as_uint(__bfloat162float(__float2bfloat16(f0 - h0))) >> 16;
  const unsigned l1 = __float_as_uint(__bfloat162float(__float2bfloat16(f1 - h1))) & 0xffff0000u;
  lw = l0 | l1;
}

// ---------------------------------------------------------------------------
// Kernel D: out = X @ proj_w + proj_b via 3-term split-bf16 MFMA,
// splitting X fp32 -> hi/lo during LDS staging (no xsplit pass).
// ---------------------------------------------------------------------------
__global__ __launch_bounds__(256) void proj3_kernel(
    const float* __restrict__ X,
    const ushort* __restrict__ WhT, const ushort* __restrict__ WlT,
    const float* __restrict__ pb, float* __restrict__ out)
{
  __shared__ unsigned Ah[64][36], Al[64][36], Bh[64][36], Bl[64][36];
  const int t    = threadIdx.x;
  const int bc   = blockIdx.x % 12, br = blockIdx.x / 12;
  const int row0 = br * 64, col0 = bc * 64;
  const int w    = t >> 6;
  const int lane = t & 63;
  const int l15  = lane & 15;
  const int quad = lane >> 4;
  const int wr   = w >> 1, wc = w & 1;

  f32x4 acc[2][2];
  #pragma unroll
  for (int i = 0; i < 2; ++i)
    #pragma unroll
    for (int j = 0; j < 2; ++j) acc[i][j] = (f32x4){0.f, 0.f, 0.f, 0.f};

  for (int kt = 0; kt < 768; kt += 64) {
    __syncthreads();
    #pragma unroll
    for (int it = 0; it < 2; ++it) {
      const int i = t + it * 256;          // 0..511
      const int r = i >> 3, j = i & 7;
      const float* xs = X + (size_t)(row0 + r) * 768 + kt + j * 8;
      const float4 xa = *(const float4*)(xs);
      const float4 xb = *(const float4*)(xs + 4);
      uint4 hv, lv;
      split2(xa.x, xa.y, hv.x, lv.x);
      split2(xa.z, xa.w, hv.y, lv.y);
      split2(xb.x, xb.y, hv.z, lv.z);
      split2(xb.z, xb.w, hv.w, lv.w);
      ((uint4*)&Ah[r][0])[j] = hv;
      ((uint4*)&Al[r][0])[j] = lv;
      ((uint4*)&Bh[r][0])[j] = *(const uint4*)(WhT + (size_t)(col0 + r) * 768 + kt + j * 8);
      ((uint4*)&Bl[r][0])[j] = *(const uint4*)(WlT + (size_t)(col0 + r) * 768 + kt + j * 8);
    }
    __syncthreads();
    #pragma unroll
    for (int ks = 0; ks < 2; ++ks) {
      const int ko = ks * 16 + quad * 4;
      uint4 ah[2], al[2], bh[2], bl[2];
      #pragma unroll
      for (int i = 0; i < 2; ++i) {
        ah[i] = *(const uint4*)&Ah[wr * 32 + i * 16 + l15][ko];
        al[i] = *(const uint4*)&Al[wr * 32 + i * 16 + l15][ko];
      }
      #pragma unroll
      for (int j = 0; j < 2; ++j) {
        bh[j] = *(const uint4*)&Bh[wc * 32 + j * 16 + l15][ko];
        bl[j] = *(const uint4*)&Bl[wc * 32 + j * 16 + l15][ko];
      }
      #pragma unroll
      for (int i = 0; i < 2; ++i)
        #pragma unroll
        for (int j = 0; j < 2; ++j) {
          acc[i][j] = mfma16(ah[i], bh[j], acc[i][j]);
          acc[i][j] = mfma16(al[i], bh[j], acc[i][j]);
          acc[i][j] = mfma16(ah[i], bl[j], acc[i][j]);
        }
    }
  }

  #pragma unroll
  for (int i = 0; i < 2; ++i)
    #pragma unroll
    for (int j = 0; j < 2; ++j) {
      const int col = col0 + wc * 32 + j * 16 + l15;
      const float bias = pb[col];
      #pragma unroll
      for (int r = 0; r < 4; ++r)
        out[(size_t)(row0 + wr * 32 + i * 16 + quad * 4 + r) * 768 + col] = acc[i][j][r] + bias;
    }
}

// ---------------------------------------------------------------------------
extern "C" void kernel_launch(void* const* d_in, const int* in_sizes, int n_in,
                              void* d_out, int out_size, void* d_ws, size_t ws_size,
                              hipStream_t stream)
{
  const float* q  = (const float*)d_in[0];
  const float* k  = (const float*)d_in[1];
  const float* v  = (const float*)d_in[2];
  const float* cw = (const float*)d_in[3];
  const float* rw = (const float*)d_in[4];
  const float* rb = (const float*)d_in[5];
  const float* bg = (const float*)d_in[6];
  const float* bb = (const float*)d_in[7];
  const float* bm = (const float*)d_in[8];
  const float* bv = (const float*)d_in[9];
  const float* pw = (const float*)d_in[10];
  const float* pb = (const float*)d_in[11];
  float* out = (float*)d_out;

  char* ws = (char*)d_ws;
  bf16*  qh = (bf16*)(ws);                         // 12,582,912 B
  bf16*  kh = (bf16*)(ws + 12582912);              // 12,582,912 B
  bf16*  vt = (bf16*)(ws + 25165824);              // 12,582,912 B (V^T)
  float* X  = (float*)(ws + 37748736);             // 25,165,824 B (fp32 attn out)
  bf16*  vhT = (bf16*)X;                           // temp vh, dead after vtrans
  // live only after attn2 (vt dead):
  ushort* WhT = (ushort*)vt;                       // 1,179,648 B
  ushort* WlT = (ushort*)((char*)vt + 1179648);    // 1,179,648 B
  // Lbuf scratch in d_out's head; proj3 overwrites all of d_out later.
  float* Lbuf = (float*)d_out;                     // 262,144 B

  hipMemsetAsync(Lbuf, 0, 262144, stream);
  conv_kernel<<<8192, 256, 0, stream>>>(q, k, v, cw, qh, kh, vhT);
  vtrans_kernel<<<1024, 256, 0, stream>>>(vhT, vt);
  hipMemsetAsync(X, 0, 25165824, stream);
  lsum_kernel<<<2048, 256, 0, stream>>>(qh, kh, Lbuf);
  attn2_kernel<<<2048, 256, 0, stream>>>(qh, kh, vt, Lbuf, rw, rb, bg, bb, bm, bv, X);
  wsplit_kernel<<<576, 256, 0, stream>>>(pw, WhT, WlT);
  proj3_kernel<<<1536, 256, 0, stream>>>(X, WhT, WlT, pb, out);
}